// Round 7
// baseline (895.098 us; speedup 1.0000x reference)
//
#include <hip/hip_runtime.h>
#include <hip/hip_bf16.h>
#include <math.h>

typedef __hip_bfloat16 bf16;
typedef short bf16x8 __attribute__((ext_vector_type(8)));
typedef float f32x4 __attribute__((ext_vector_type(4)));

#define B_    256
#define SEQ_  200
#define H_    256
#define FREQ_ 9
#define NSEG_ 26
#define LDS64 64   // linear LDS rows (64 shorts = 128 B); bank spread via XOR swizzle

__device__ __forceinline__ float ldb(const bf16* p, size_t i){ return __bfloat162float(p[i]); }
__device__ __forceinline__ void stb(bf16* p, size_t i, float v){ p[i] = __float2bfloat16(v); }
__device__ __forceinline__ short f2b(float v){ union{bf16 b; short s;} c; c.b = __float2bfloat16(v); return c.s; }
__device__ __forceinline__ unsigned short f2bu(float v){ union{bf16 b; unsigned short s;} c; c.b = __float2bfloat16(v); return c.s; }
__device__ __forceinline__ float b2f(unsigned short u){ union{unsigned short s; bf16 b;} c; c.s = u; return __bfloat162float(c.b); }
// tanh-form gelu (max dev vs erf-form ~3.7e-4, far below bf16 activation quantization).
__device__ __forceinline__ float gelu_(float x){
  float y  = 0.7978845608f*(x + 0.044715f*x*x*x);
  float ay = fabsf(y);
  float e  = __expf(-2.f*ay);
  float th = 1.f - 2.f*e*__builtin_amdgcn_rcpf(1.f + e);
  th = copysignf(th, y);
  return 0.5f*x*(1.f + th);
}

__device__ __constant__ float CT16[16] = {
  1.0f, 0.9238795325f, 0.7071067812f, 0.3826834324f, 0.0f, -0.3826834324f, -0.7071067812f, -0.9238795325f,
 -1.0f,-0.9238795325f,-0.7071067812f,-0.3826834324f, 0.0f,  0.3826834324f, 0.7071067812f,  0.9238795325f};
__device__ __constant__ float ST16[16] = {
  0.0f, 0.3826834324f, 0.7071067812f, 0.9238795325f, 1.0f,  0.9238795325f, 0.7071067812f,  0.3826834324f,
  0.0f,-0.3826834324f,-0.7071067812f,-0.9238795325f,-1.0f, -0.9238795325f,-0.7071067812f, -0.3826834324f};

// =================== shared MFMA GEMM machinery ===================
__device__ __forceinline__ void gload16(const short* g, short* l){
  __builtin_amdgcn_global_load_lds(
      (const __attribute__((address_space(1))) unsigned int*)(const void*)g,
      (__attribute__((address_space(3))) unsigned int*)(void*)l, 16, 0, 0);
}

// stage ROWS x 64 bf16 tile from global [row][k] (k-contiguous) into LDS [ROWS][64]
template<int ROWS>
__device__ __forceinline__ void stage_tile(short* lds, const short* src, int rstride, int tid){
  int rl = tid >> 3;        // row within 32-row group
  int c  = tid & 7;         // 16B chunk slot (linear in LDS)
  #pragma unroll
  for(int p=0; p<ROWS/32; p++){
    int r = p*32 + rl;
    int csrc = c ^ (r & 7); // inverse swizzle on the global side
    gload16(src + (size_t)r*rstride + csrc*8, lds + r*LDS64 + c*8);
  }
}

// one BK=64 step: wave computes 64x64 via 4x4 grid of 16x16x32 MFMA
__device__ __forceinline__ void mma_bk64(const short* lA, const short* lB, int wm, int wn,
                                         int lane, f32x4 acc[4][4]){
  int m_l = lane & 15, quad = lane >> 4;
  int sw = m_l & 7;
  #pragma unroll
  for(int ks=0; ks<64; ks+=32){
    int cs = (((ks>>3) + quad) ^ sw) * 8;
    bf16x8 a[4], b[4];
    #pragma unroll
    for(int i=0;i<4;i++) a[i] = *(const bf16x8*)&lA[(wm + i*16 + m_l)*LDS64 + cs];
    #pragma unroll
    for(int j=0;j<4;j++) b[j] = *(const bf16x8*)&lB[(wn + j*16 + m_l)*LDS64 + cs];
    #pragma unroll
    for(int i=0;i<4;i++)
      #pragma unroll
      for(int j=0;j<4;j++)
        acc[i][j] = __builtin_amdgcn_mfma_f32_16x16x32_bf16(a[i], b[j], acc[i][j], 0,0,0);
  }
}

// =================== prep: weight repack (fp32 -> transposed bf16) ===================
__global__ __launch_bounds__(256) void k_prep_b1(const float* __restrict__ w1, short* __restrict__ B1t){
  int g = blockIdx.x;
  int jt = g & 7, ht = (g>>3)&3, p = (g>>5)&1, s = g>>6;   // 26*64 = 1664 blocks
  __shared__ float tile[64][65];
  int t = threadIdx.x;
  const float* src = w1 + (size_t)p*3407872 + (size_t)s*131072;
  #pragma unroll
  for(int q=0;q<16;q++){
    int r = q*4 + (t>>6), c = t & 63;
    tile[r][c] = src[(size_t)(ht*64 + r)*512 + jt*64 + c];   // W1p[h][j]
  }
  __syncthreads();
  int n_l = t >> 2, kc = (t & 3)*16;
  short tA[16] __attribute__((aligned(16)));
  short tB[16] __attribute__((aligned(16)));
  #pragma unroll
  for(int i=0;i<16;i++){
    float v = tile[kc+i][n_l];
    tA[i] = (p==0) ? f2b(v) : f2b(-v);
    tB[i] = f2b(v);
  }
  int j = jt*64 + n_l, h = ht*64 + kc;
  size_t d1, d2;
  if(p==0){ d1 = ((size_t)(s*1024 + j))*512 + h;
            d2 = ((size_t)(s*1024 + 512 + j))*512 + 256 + h; }
  else    { d1 = ((size_t)(s*1024 + j))*512 + 256 + h;
            d2 = ((size_t)(s*1024 + 512 + j))*512 + h; }
  *(int4*)&B1t[d1] = *(int4*)&tA[0]; *(int4*)&B1t[d1+8] = *(int4*)&tA[8];
  *(int4*)&B1t[d2] = *(int4*)&tB[0]; *(int4*)&B1t[d2+8] = *(int4*)&tB[8];
}

__global__ __launch_bounds__(256) void k_prep_b2(const float* __restrict__ w2,
                                                 short* __restrict__ B2r, short* __restrict__ B2i){
  int g = blockIdx.x;
  int ht = g & 3, jt = (g>>2)&7, s = g>>5;                  // 26*32 = 832 blocks
  __shared__ float t0[64][65], t1[64][65];
  int t = threadIdx.x;
  const float* s0 = w2 + (size_t)s*131072;
  const float* s1 = w2 + 3407872 + (size_t)s*131072;
  #pragma unroll
  for(int q=0;q<16;q++){
    int r = q*4 + (t>>6), c = t & 63;
    t0[r][c] = s0[(size_t)(jt*64 + r)*256 + ht*64 + c];
    t1[r][c] = s1[(size_t)(jt*64 + r)*256 + ht*64 + c];
  }
  __syncthreads();
  int n_l = t >> 2, jc = (t & 3)*16;
  short ta[16] __attribute__((aligned(16)));
  short tb[16] __attribute__((aligned(16)));
  short tc[16] __attribute__((aligned(16)));
  #pragma unroll
  for(int i=0;i<16;i++){
    float v0 = t0[jc+i][n_l], v1 = t1[jc+i][n_l];
    ta[i] = f2b(v0); tb[i] = f2b(-v1); tc[i] = f2b(v0+v1);
  }
  int n = ht*64 + n_l, j = jt*64 + jc;
  size_t dr = ((size_t)(s*256 + n))*1024 + j;
  size_t di = ((size_t)(s*256 + n))*512 + j;
  *(int4*)&B2r[dr]     = *(int4*)&ta[0]; *(int4*)&B2r[dr+8]     = *(int4*)&ta[8];
  *(int4*)&B2r[dr+512] = *(int4*)&tb[0]; *(int4*)&B2r[dr+520]   = *(int4*)&tb[8];
  *(int4*)&B2i[di]     = *(int4*)&tc[0]; *(int4*)&B2i[di+8]     = *(int4*)&tc[8];
}

// generic transpose fp32 [R][C] -> bf16 [C][R]
__global__ __launch_bounds__(256) void k_transp(const float* __restrict__ src, short* __restrict__ dst,
                                                int R, int C){
  int ct = blockIdx.x % (C/64);
  int rt = blockIdx.x / (C/64);
  __shared__ float tile[64][65];
  int t = threadIdx.x;
  #pragma unroll
  for(int p=0;p<16;p++){
    int r = p*4 + (t>>6), c = t & 63;
    tile[r][c] = src[(size_t)(rt*64 + r)*C + ct*64 + c];
  }
  __syncthreads();
  int row_out = t >> 2, rc = (t & 3)*16;
  short tmp[16] __attribute__((aligned(16)));
  #pragma unroll
  for(int i=0;i<16;i++) tmp[i] = f2b(tile[rc+i][row_out]);
  size_t base = (size_t)(ct*64 + row_out)*R + rt*64 + rc;
  *(int4*)&dst[base] = *(int4*)&tmp[0]; *(int4*)&dst[base+8] = *(int4*)&tmp[8];
}

// prep for MFMA segment mixer
__global__ __launch_bounds__(256) void k_prep_sm(const float* __restrict__ w1, const float* __restrict__ w2,
                                                 short* __restrict__ B1sm, short* __restrict__ B2sm){
  int f = blockIdx.x;  // 9 blocks
  int t = threadIdx.x;
  for(int idx=t; idx<8192; idx+=256){
    int jp = idx >> 6, k = idx & 63;
    float v = 0.f;
    if(jp < 104){
      int j = (jp < 52) ? jp : jp - 52;
      if(k < 26){
        int s = k;
        v = (jp < 52) ? w1[f*1352 + s*52 + j] : w1[12168 + f*1352 + s*52 + j];
      } else if(k >= 32 && k < 58){
        int s = k - 32;
        v = (jp < 52) ? -w1[12168 + f*1352 + s*52 + j] : w1[f*1352 + s*52 + j];
      }
    }
    B1sm[(size_t)f*8192 + idx] = f2b(v);
  }
  for(int idx=t; idx<8192; idx+=256){
    int sop = idx >> 7, k = idx & 127;
    float v = 0.f;
    if(sop < 26){
      if(k < 52)       v = w2[f*1352 + k*26 + sop];
      else if(k < 104) v = -w2[12168 + f*1352 + (k-52)*26 + sop];
    } else if(sop < 52){
      int so = sop - 26;
      if(k >= 52 && k < 104)
        v = w2[f*1352 + (k-52)*26 + so] + w2[12168 + f*1352 + (k-52)*26 + so];
    }
    B2sm[(size_t)f*8192 + idx] = f2b(v);
  }
}

// prep for MFMA frequency mixer
__global__ __launch_bounds__(256) void k_prep_fm(const float* __restrict__ w1, const float* __restrict__ w2,
                                                 short* __restrict__ B1fm, short* __restrict__ B2fm){
  int s = blockIdx.x;  // 26 blocks
  int t = threadIdx.x;
  for(int idx=t; idx<1536; idx+=256){
    int n = idx >> 5, k = idx & 31;
    float v = 0.f;
    if(n < 18){
      if(k < 9)       v = w1[s*162 + k*18 + n];
      else if(k < 18) v = -w1[4212 + s*162 + (k-9)*18 + n];
    } else if(n < 36){
      int j = n - 18;
      if(k < 9)       v = w1[4212 + s*162 + k*18 + j];
      else if(k < 18) v = w1[s*162 + (k-9)*18 + j];
    }
    B1fm[s*1536 + idx] = f2b(v);
  }
  for(int idx=t; idx<2048; idx+=256){
    int n = idx >> 6, k = idx & 63;
    float v = 0.f;
    if(n < 9){
      if(k < 18)      v = w2[s*162 + k*9 + n];
      else if(k < 36) v = -w2[4212 + s*162 + (k-18)*9 + n];
    } else if(n < 18){
      int f = n - 9;
      if(k >= 18 && k < 36)
        v = w2[s*162 + (k-18)*9 + f] + w2[4212 + s*162 + (k-18)*9 + f];
    }
    B2fm[s*2048 + idx] = f2b(v);
  }
}

// transpose conv_w [s][h][f] -> cwT [s][f][h] so the gating gather is coalesced
__global__ __launch_bounds__(256) void k_prep_cw(const float* __restrict__ cw, float* __restrict__ cwT){
  int s = blockIdx.x; int t = threadIdx.x;  // 26 blocks
  __shared__ float tile[2304];
  for(int i=t; i<2304; i+=256) tile[i] = cw[s*2304 + i];
  __syncthreads();
  #pragma unroll
  for(int f=0; f<9; f++) cwT[(s*9+f)*256 + t] = tile[t*9+f];
}

// =================== Kernel 1: STFT(MFMA) + gating + frequency mixer (MFMA) ===================
// v3: DFT runs as one K=32 MFMA pass (frames bf16 in lFt[256][40], DFT matrix +-0.25*CT/ST
// built in LDS; rows 18..31 zero so spec scatter auto-zeroes lX pad cols). Gating reads
// bf16 spec from LDS + shuffle-reduce (replaces 8-barrier tree). wv folds into layer-1
// epilogue (spec.B1 is linear in spec).
#define LX1 40
#define LG1 72
__global__ __launch_bounds__(256) void k_sfm3(const float* __restrict__ inp,
                                              const float* __restrict__ cwT, const float* __restrict__ cb,
                                              const short* __restrict__ B1fm, const short* __restrict__ B2fm,
                                              const float* __restrict__ bb1, const float* __restrict__ bb2,
                                              bf16* __restrict__ oR, bf16* __restrict__ oI){
  int blk = blockIdx.x; int b = blk / NSEG_; int s = blk % NSEG_; int t = threadIdx.x;
  int lane = t & 63, wave = t >> 6, m_l = lane & 15, quad = lane >> 4;
  __shared__ __align__(16) short sm[20736];   // 41.5 KB
  __shared__ float lb1f[48];
  __shared__ float wred[4];
  short* lFt  = sm;           // [256][LX1] frames (phase 0-1); then lX spec overlay (phase 2+)
  short* lX   = sm;
  short* lB1  = sm + 10240;   // [48][LX1]
  short* lDft = sm + 12160;   // [32][LX1] DFT matrix (dead after DFT MFMA)
  short* lG   = sm;           // [256][LG1] overlay after layer1
  short* lB2  = sm + 18432;   // [32][LG1] persistent

  // ---- phase 0: stage weights, DFT matrix, frames ----
  {
    const short* src1 = B1fm + s*1536;
    for(int idx=t; idx<768; idx+=256){
      int r = idx >> 4, c = idx & 15;
      *(unsigned*)&lB1[r*LX1 + c*2] = *(const unsigned*)&src1[r*32 + c*2];
    }
    const short* src2 = B2fm + s*2048;
    for(int idx=t; idx<1024; idx+=256){
      int r = idx >> 5, c = idx & 31;
      *(unsigned*)&lB2[r*LG1 + c*2] = *(const unsigned*)&src2[r*64 + c*2];
    }
    if(t < 48) lb1f[t] = (t < 18) ? bb1[s*18 + t] : (t < 36 ? bb1[468 + s*18 + (t-18)] : 0.f);
    // DFT matrix [32n][32k]: n<9: 0.25*CT16[nk]; 9..17: -0.25*ST16[(n-9)k]; else 0 (k>=16 zero)
    #pragma unroll
    for(int q=0;q<4;q++){
      int idx = q*256 + t;
      int n = idx >> 5, k = idx & 31;
      float v = 0.f;
      if(k < 16){
        if(n < 9)       v =  0.25f*CT16[(n*k) & 15];
        else if(n < 18) v = -0.25f*ST16[((n-9)*k) & 15];
      }
      lDft[n*LX1 + k] = f2b(v);
    }
  }
  // gating weights (coalesced)
  float cwv[9];
  #pragma unroll
  for(int f=0;f<9;f++) cwv[f] = cwT[(s*9+f)*256 + t];
  // frames: thread t = column h; 16 coalesced loads; k 16..31 zeroed (K=32 MFMA)
  {
    int t0 = s*8 - 8;
    unsigned pk[8];
    #pragma unroll
    for(int c=0;c<8;c++){
      int t1 = t0 + 2*c, t2 = t0 + 2*c + 1;
      float v1 = (t1>=0 && t1<SEQ_) ? inp[(size_t)(b*SEQ_+t1)*H_ + t] : 0.0f;
      float v2 = (t2>=0 && t2<SEQ_) ? inp[(size_t)(b*SEQ_+t2)*H_ + t] : 0.0f;
      pk[c] = (unsigned)f2bu(v1) | ((unsigned)f2bu(v2) << 16);
    }
    *(int4*)&lFt[t*LX1 + 0] = *(const int4*)&pk[0];
    *(int4*)&lFt[t*LX1 + 8] = *(const int4*)&pk[4];
    int4 z = {0,0,0,0};
    *(int4*)&lFt[t*LX1 + 16] = z;
    *(int4*)&lFt[t*LX1 + 24] = z;
  }
  __syncthreads();

  // ---- DFT MFMA: spec[h][n] = frames[h][k] . Dft[n][k], K=32 ----
  int h0 = wave*64;
  f32x4 accD[4][2];
  {
    bf16x8 a[4], bD[2];
    #pragma unroll
    for(int i=0;i<4;i++) a[i] = *(const bf16x8*)&lFt[(h0 + i*16 + m_l)*LX1 + quad*8];
    #pragma unroll
    for(int j=0;j<2;j++) bD[j] = *(const bf16x8*)&lDft[(j*16 + m_l)*LX1 + quad*8];
    #pragma unroll
    for(int i=0;i<4;i++)
      #pragma unroll
      for(int j=0;j<2;j++)
        accD[i][j] = __builtin_amdgcn_mfma_f32_16x16x32_bf16(a[i], bD[j], (f32x4){0.f,0.f,0.f,0.f}, 0,0,0);
  }
  __syncthreads();   // lFt/lDft reads complete before spec overlay

  // ---- scatter spec -> lX[h][n] (all 32 n; n>=18 are exact zeros from zero Dft rows) ----
  #pragma unroll
  for(int i=0;i<4;i++)
    #pragma unroll
    for(int j=0;j<2;j++){
      int n = j*16 + m_l;
      #pragma unroll
      for(int r=0;r<4;r++){
        int h = h0 + i*16 + quad*4 + r;
        lX[h*LX1 + n] = f2b(accD[i][j][r]);
      }
    }
  __syncthreads();

  // ---- gating: thread t reads its 20 cols, |spec| dot cw, shuffle-reduce ----
  float g = 0.f;
  {
    unsigned u[10];
    *(int4*)&u[0] = *(const int4*)&lX[t*LX1 + 0];
    *(int4*)&u[4] = *(const int4*)&lX[t*LX1 + 8];
    *(int2*)&u[8] = *(const int2*)&lX[t*LX1 + 16];
    float xv[18];
    #pragma unroll
    for(int c=0;c<9;c++){ xv[2*c] = b2f((unsigned short)(u[c]&0xFFFF)); xv[2*c+1] = b2f((unsigned short)(u[c]>>16)); }
    #pragma unroll
    for(int f=0;f<9;f++){
      float xr = xv[f], xi = xv[9+f];
      g += sqrtf(xr*xr + xi*xi) * cwv[f];
    }
    #pragma unroll
    for(int msk=1; msk<64; msk<<=1) g += __shfl_xor(g, msk);
    if(lane == 0) wred[wave] = g;
  }
  __syncthreads();
  float wv = wred[0]+wred[1]+wred[2]+wred[3] + cb[s] + __expf((float)(s - (NSEG_-1)));

  // ---- layer1 MFMA: N=48, K=32 (lX cols 18..31 are zero) ----
  f32x4 acc1[4][3];
  {
    bf16x8 a1[4], b1v[3];
    #pragma unroll
    for(int i=0;i<4;i++) a1[i] = *(const bf16x8*)&lX[(h0 + i*16 + m_l)*LX1 + quad*8];
    #pragma unroll
    for(int j=0;j<3;j++) b1v[j] = *(const bf16x8*)&lB1[(j*16 + m_l)*LX1 + quad*8];
    #pragma unroll
    for(int i=0;i<4;i++)
      #pragma unroll
      for(int j=0;j<3;j++)
        acc1[i][j] = __builtin_amdgcn_mfma_f32_16x16x32_bf16(a1[i], b1v[j], (f32x4){0.f,0.f,0.f,0.f}, 0,0,0);
  }
  __syncthreads();   // lX/lB1 reads done before lG overlay

  // ---- gelu(wv*acc1 + bias) -> lG (n 36..47 land exactly 0) ----
  #pragma unroll
  for(int i=0;i<4;i++){
    #pragma unroll
    for(int j=0;j<3;j++){
      int n = j*16 + m_l;
      float bias = lb1f[n];
      #pragma unroll
      for(int r=0;r<4;r++){
        int row = h0 + i*16 + quad*4 + r;
        lG[row*LG1 + n] = f2b(gelu_(acc1[i][j][r]*wv + bias));
      }
    }
  }
  // zero pad cols 48..63 of own row
  #pragma unroll
  for(int c=0;c<8;c++) *(unsigned*)&lG[t*LG1 + 48 + c*2] = 0u;
  __syncthreads();

  // ---- layer2 MFMA: N=32 (18 used), K=64 ----
  f32x4 acc2[4][2];
  #pragma unroll
  for(int i=0;i<4;i++)
    #pragma unroll
    for(int j=0;j<2;j++) acc2[i][j] = (f32x4){0.f,0.f,0.f,0.f};
  #pragma unroll
  for(int ks=0; ks<64; ks+=32){
    bf16x8 a2[4], b2v[2];
    #pragma unroll
    for(int i=0;i<4;i++) a2[i] = *(const bf16x8*)&lG[(h0 + i*16 + m_l)*LG1 + ks + quad*8];
    #pragma unroll
    for(int j=0;j<2;j++) b2v[j] = *(const bf16x8*)&lB2[(j*16 + m_l)*LG1 + ks + quad*8];
    #pragma unroll
    for(int i=0;i<4;i++)
      #pragma unroll
      for(int j=0;j<2;j++)
        acc2[i][j] = __builtin_amdgcn_mfma_f32_16x16x32_bf16(a2[i], b2v[j], acc2[i][j], 0,0,0);
  }

  // ---- epilogue: +b2, write oR (n<9) / oI (9<=n<18) ----
  #pragma unroll
  for(int j=0;j<2;j++){
    int n = j*16 + m_l;
    if(n < 18){
      bool isI = n >= 9;
      int f = isI ? n-9 : n;
      float bias = isI ? bb2[234 + s*9 + f] : bb2[s*9 + f];
      bf16* outp = isI ? oI : oR;
      size_t base = ((size_t)(s*B_ + b)*FREQ_ + f)*H_;
      #pragma unroll
      for(int i=0;i<4;i++){
        int h = h0 + i*16 + quad*4;
        short pk[4] __attribute__((aligned(8)));
        #pragma unroll
        for(int r=0;r<4;r++) pk[r] = f2b(acc2[i][j][r] + bias);
        *(int2*)&outp[base + h] = *(const int2*)&pk[0];
      }
    }
  }
}

// =================== Kernel 4a: channel mixer layer1 (MFMA) ===================
__global__ __launch_bounds__(256) void k_cm1(const bf16* __restrict__ Xr, const bf16* __restrict__ Xi,
                                             const short* __restrict__ B1t, const float* __restrict__ b1bias,
                                             short* __restrict__ H, int half){
  int nt = blockIdx.x & 7, mt = (blockIdx.x >> 3) % 9, s = blockIdx.x / 72;
  int tid = threadIdx.x, lane = tid & 63, wave = tid >> 6;
  int wm = (wave & 1)*64, wn = (wave >> 1)*64;
  __shared__ __align__(16) short lA[128*LDS64];
  __shared__ __align__(16) short lB[128*LDS64];
  f32x4 acc[4][4];
  #pragma unroll
  for(int i=0;i<4;i++)
    #pragma unroll
    for(int j=0;j<4;j++) acc[i][j] = (f32x4){0.f,0.f,0.f,0.f};
  int rowbase = half*1152 + mt*128;
  const short* Bbase = B1t + ((size_t)(s*1024 + nt*128))*512;
  for(int k0=0; k0<512; k0+=64){
    const short* Asrc = (k0 < 256)
      ? (const short*)(Xr + ((size_t)(s*2304 + rowbase))*256 + k0)
      : (const short*)(Xi + ((size_t)(s*2304 + rowbase))*256 + (k0-256));
    stage_tile<128>(lA, Asrc, 256, tid);
    stage_tile<128>(lB, Bbase + k0, 512, tid);
    __syncthreads();
    mma_bk64(lA, lB, wm, wn, lane, acc);
    __syncthreads();
  }
  int m_l = lane & 15, quad = lane >> 4;
  #pragma unroll
  for(int i=0;i<4;i++){
    #pragma unroll
    for(int j=0;j<4;j++){
      int n = nt*128 + wn + j*16 + m_l;
      float bias = (n < 512) ? b1bias[s*512 + n] : b1bias[13312 + s*512 + (n-512)];
      #pragma unroll
      for(int r=0;r<4;r++){
        int mrow = wm + i*16 + quad*4 + r;
        float v = gelu_(acc[i][j][r] + bias);
        H[((size_t)(s*1152 + mt*128 + mrow))*1024 + n] = f2b(v);
      }
    }
  }
}

// =================== Kernel 4b: channel mixer layer2 (MFMA) ===================
__global__ __launch_bounds__(256) void k_cm2(const short* __restrict__ H,
                                             const short* __restrict__ B2r, const short* __restrict__ B2i,
                                             const float* __restrict__ b2bias,
                                             bf16* __restrict__ oR, bf16* __restrict__ oI, int half){
  int nt = blockIdx.x & 3, mt = (blockIdx.x>>2) % 9, s = blockIdx.x / 36;
  int tid = threadIdx.x, lane = tid & 63, wave = tid >> 6;
  int wm = (wave & 1)*64, wn = (wave >> 1)*64;
  bool isOi = nt >= 2;
  int n0 = (nt & 1)*128;
  int K = isOi ? 512 : 1024;
  int Aoff = isOi ? 512 : 0;
  int Bstride = isOi ? 512 : 1024;
  const short* Bb = isOi ? (B2i + ((size_t)(s*256 + n0))*512) : (B2r + ((size_t)(s*256 + n0))*1024);
  const short* Ab = H + ((size_t)(s*1152 + mt*128))*1024 + Aoff;
  __shared__ __align__(16) short lA[128*LDS64];
  __shared__ __align__(16) short lB[128*LDS64];
  f32x4 acc[4][4];
  #pragma unroll
  for(int i=0;i<4;i++)
    #pragma unroll
    for(int j=0;j<4;j++) acc[i][j] = (f32x4){0.f,0.f,0.f,0.f};
  for(int k0=0; k0<K; k0+=64){
    stage_tile<128>(lA, Ab + k0, 1024, tid);
    stage_tile<128>(lB, Bb + k0, Bstride, tid);
    __syncthreads();
    mma_bk64(lA, lB, wm, wn, lane, acc);
    __syncthreads();
  }
  int m_l = lane & 15, quad = lane >> 4;
  bf16* outp = isOi ? oI : oR;
  #pragma unroll
  for(int i=0;i<4;i++){
    #pragma unroll
    for(int j=0;j<4;j++){
      int n = n0 + wn + j*16 + m_l;
      float bias = b2bias[(isOi ? 6656 : 0) + s*256 + n];
      #pragma unroll
      for(int r=0;r<4;r++){
        int mrow = wm + i*16 + quad*4 + r;
        int rowg = half*1152 + mt*128 + mrow;
        stb(outp, ((size_t)rowg*NSEG_ + s)*256 + n, acc[i][j][r] + bias);
      }
    }
  }
}

// =================== Kernel 5: segment mixer (MFMA) ===================
#define LDX 72
#define LDG 136
__global__ __launch_bounds__(256) void k_smm(const bf16* __restrict__ iR, const bf16* __restrict__ iI,
                                             const short* __restrict__ B1sm, const short* __restrict__ B2sm,
                                             const float* __restrict__ bb1, const float* __restrict__ bb2,
                                             bf16* __restrict__ oR, bf16* __restrict__ oI){
  int blk = blockIdx.x;
  int f  = blk % 9;
  int hh = (blk/9) & 1;
  int bq = blk / 18;
  int t = threadIdx.x, lane = t & 63, wave = t >> 6;
  int m_l = lane & 15, quad = lane >> 4;
  __shared__ __align__(16) short sm[18432 + 8704];  // 54.3 KB
  __shared__ float lb1[128];
  short* lX  = sm;                 // [128][LDX]
  short* lB1 = sm + 128*LDX;       // [128][LDX]
  short* lG  = sm;                 // [128][LDG] overlay (after barrier)
  short* lB2 = sm + 18432;         // [64][LDG]
  int rbase = (bq*9 + f)*26;

  #pragma unroll
  for(int it=0; it<4; it++){
    int idx = it*256 + t;          // 1024 x 16B
    int r = idx >> 3, c = idx & 7;
    *(int4*)&lB1[r*LDX + c*8] = *(const int4*)&B1sm[(size_t)f*8192 + r*64 + c*8];
  }
  #pragma unroll
  for(int it=0; it<4; it++){
    int idx = it*256 + t;
    int r = idx >> 4, c = idx & 15;
    *(int4*)&lB2[r*LDG + c*8] = *(const int4*)&B2sm[(size_t)f*8192 + r*128 + c*8];
  }
  if(t < 128) lb1[t] = (t < 52) ? bb1[f*52 + t] : (t < 104 ? bb1[468 + f*52 + (t-52)] : 0.f);

  int hl = t & 127, g = t >> 7;
  #pragma unroll
  for(int it=0; it<13; it++){
    int a   = it*2 + g;
    int arr = a >= 13;
    int pr  = arr ? a-13 : a;
    int s0  = pr*2;
    const bf16* src = arr ? iI : iR;
    unsigned v0 = *(const unsigned short*)&src[((size_t)(rbase+s0  ))*256 + hh*128 + hl];
    unsigned v1 = *(const unsigned short*)&src[((size_t)(rbase+s0+1))*256 + hh*128 + hl];
    *(unsigned*)&lX[hl*LDX + arr*32 + s0] = v0 | (v1 << 16);
  }
  {
    int zb = g ? 58 : 26;
    #pragma unroll
    for(int i=0;i<3;i++) *(unsigned*)&lX[hl*LDX + zb + i*2] = 0u;
  }
  __syncthreads();

  int h0 = wave*32;
  f32x4 acc1[2][8];
  #pragma unroll
  for(int i=0;i<2;i++)
    #pragma unroll
    for(int j=0;j<8;j++) acc1[i][j] = (f32x4){0.f,0.f,0.f,0.f};
  #pragma unroll
  for(int ks=0; ks<64; ks+=32){
    bf16x8 av[2], bv[8];
    #pragma unroll
    for(int i=0;i<2;i++) av[i] = *(const bf16x8*)&lX[(h0 + i*16 + m_l)*LDX + ks + quad*8];
    #pragma unroll
    for(int j=0;j<8;j++) bv[j] = *(const bf16x8*)&lB1[(j*16 + m_l)*LDX + ks + quad*8];
    #pragma unroll
    for(int i=0;i<2;i++)
      #pragma unroll
      for(int j=0;j<8;j++)
        acc1[i][j] = __builtin_amdgcn_mfma_f32_16x16x32_bf16(av[i], bv[j], acc1[i][j], 0,0,0);
  }
  __syncthreads();

  #pragma unroll
  for(int i=0;i<2;i++){
    #pragma unroll
    for(int j=0;j<8;j++){
      int jp = j*16 + m_l;
      float bias = lb1[jp];
      #pragma unroll
      for(int r=0;r<4;r++){
        int hrow = h0 + i*16 + quad*4 + r;
        lG[hrow*LDG + jp] = f2b(gelu_(acc1[i][j][r] + bias));
      }
    }
  }
  __syncthreads();

  f32x4 acc2[2][4];
  #pragma unroll
  for(int i=0;i<2;i++)
    #pragma unroll
    for(int j=0;j<4;j++) acc2[i][j] = (f32x4){0.f,0.f,0.f,0.f};
  #pragma unroll
  for(int ks=0; ks<128; ks+=32){
    bf16x8 av[2], bv[4];
    #pragma unroll
    for(int i=0;i<2;i++) av[i] = *(const bf16x8*)&lG[(h0 + i*16 + m_l)*LDG + ks + quad*8];
    #pragma unroll
    for(int j=0;j<4;j++) bv[j] = *(const bf16x8*)&lB2[(j*16 + m_l)*LDG + ks + quad*8];
    #pragma unroll
    for(int i=0;i<2;i++)
      #pragma unroll
      for(int j=0;j<4;j++)
        acc2[i][j] = __builtin_amdgcn_mfma_f32_16x16x32_bf16(av[i], bv[j], acc2[i][j], 0,0,0);
  }

  #pragma unroll
  for(int j=0;j<4;j++){
    int sop = j*16 + m_l;
    if(sop < 52){
      int arr = sop >= 26;
      int so  = sop - (arr ? 26 : 0);
      float bias = bb2[(arr ? 234 : 0) + f*26 + so];
      bf16* outp = arr ? oI : oR;
      #pragma unroll
      for(int i=0;i<2;i++){
        int h = hh*128 + h0 + i*16 + quad*4;
        short pk[4] __attribute__((aligned(8)));
        #pragma unroll
        for(int r=0;r<4;r++) pk[r] = f2b(acc2[i][j][r] + bias);
        *(int2*)&outp[((size_t)(rbase + so))*256 + h] = *(const int2*)&pk[0];
      }
    }
  }
}

// =================== Kernel 6: iSTFT + residual + LayerNorm (octet-fused) ===================
__global__ __launch_bounds__(256) void k_ist8(const bf16* __restrict__ iR, const bf16* __restrict__ iI,
                                              const float* __restrict__ inp,
                                              const float* __restrict__ lnw, const float* __restrict__ lnb,
                                              float* __restrict__ hs, bf16* __restrict__ hsb){
  int blk = blockIdx.x; int b = blk / 25; int o = blk % 25; int h = threadIdx.x;
  int lane = h & 63, wave = h >> 6;
  float rr[2][9], ii[2][8];
  #pragma unroll
  for(int p=0;p<2;p++){
    int s = o + p;
    size_t base = (size_t)b*FREQ_*NSEG_ + s;
    #pragma unroll
    for(int f=0;f<9;f++) rr[p][f] = ldb(iR, (base + f*NSEG_)*256 + h);
    #pragma unroll
    for(int f=1;f<8;f++) ii[p][f] = ldb(iI, (base + f*NSEG_)*256 + h);
  }
  float z[8];
  #pragma unroll
  for(int dt=0; dt<8; dt++){
    float v  = rr[0][0] + rr[1][0];
    float s8 = rr[0][8] + rr[1][8];
    v += (dt & 1) ? -s8 : s8;
    #pragma unroll
    for(int f=1;f<8;f++){
      int m1 = (f*(dt+8)) & 15;
      int m2 = (f*dt) & 15;
      v += 2.f*(rr[0][f]*CT16[m1] - ii[0][f]*ST16[m1]);
      v += 2.f*(rr[1][f]*CT16[m2] - ii[1][f]*ST16[m2]);
    }
    int t = o*8 + dt;
    z[dt] = 0.125f*v + inp[(size_t)(b*SEQ_+t)*H_ + h];
  }
  __shared__ float wsum[8][4], wsq[8][4];
  #pragma unroll
  for(int dt=0; dt<8; dt++){
    float sv = z[dt], sq = z[dt]*z[dt];
    #pragma unroll
    for(int msk=1; msk<64; msk<<=1){ sv += __shfl_xor(sv, msk); sq += __shfl_xor(sq, msk); }
    if(lane == 0){ wsum[dt][wave] = sv; wsq[dt][wave] = sq; }
  }
  __syncthreads();
  float gw = lnw[h], gb = lnb[h];
  #pragma unroll
  for(int dt=0; dt<8; dt++){
    float s1 = wsum[dt][0]+wsum[dt][1]+wsum[dt][2]+wsum[dt][3];
    float s2 = wsq[dt][0]+wsq[dt][1]+wsq[dt][2]+wsq[dt][3];
    float mean = s1*(1.f/256.f);
    float var  = s2*(1.f/256.f) - mean*mean;
    float inv  = rsqrtf(var + 1e-12f);
    float ov = gw*(z[dt]-mean)*inv + gb;
    int t = o*8 + dt;
    size_t oi = (size_t)(b*SEQ_+t)*H_ + h;
    hs[oi] = ov;
    stb(hsb, oi, ov);
  }
}

// =================== Kernel 7: FFN layer1 (MFMA, 256->1024, gelu) ===================
__global__ __launch_bounds__(256) void k_ff1m(const short* __restrict__ hsb, const short* __restrict__ fw1t,
                                              const float* __restrict__ fb1, short* __restrict__ hid, int row0){
  int nt = blockIdx.x & 7, mt = blockIdx.x >> 3;      // mt 0..199
  int tid = threadIdx.x, lane = tid & 63, wave = tid >> 6;
  int wm = (wave & 1)*64, wn = (wave >> 1)*64;
  __shared__ __align__(16) short lA[128*LDS64];
  __shared__ __align__(16) short lB[128*LDS64];
  f32x4 acc[4][4];
  #pragma unroll
  for(int i=0;i<4;i++)
    #pragma unroll
    for(int j=0;j<4;j++) acc[i][j] = (f32x4){0.f,0.f,0.f,0.f};
  const short* Ab = hsb + ((size_t)(row0 + mt*128))*256;
  const short* Bb = fw1t + ((size_t)(nt*128))*256;
  for(int k0=0; k0<256; k0+=64){
    stage_tile<128>(lA, Ab + k0, 256, tid);
    stage_tile<128>(lB, Bb + k0, 256, tid);
    __syncthreads();
    mma_bk64(lA, lB, wm, wn, lane, acc);
    __syncthreads();
  }
  int m_l = lane & 15, quad = lane >> 4;
  #pragma unroll
  for(int i=0;i<4;i++){
    #pragma unroll
    for(int j=0;j<4;j++){
      int n = nt*128 + wn + j*16 + m_l;
      float bias = fb1[n];
      #pragma unroll
      for(int r=0;r<4;r++){
        int mrow = wm + i*16 + quad*4 + r;
        hid[((size_t)(mt*128 + mrow))*1024 + n] = f2b(gelu_(acc[i][j][r] + bias));
      }
    }
  }
}

// =================== Kernel 8: FFN layer2 (MFMA) + residual + LayerNorm ===================
__global__ __launch_bounds__(256) void k_ff2m(const short* __restrict__ hid, const short* __restrict__ fw2t,
                                              const float* __restrict__ fb2, const float* __restrict__ hs,
                                              const float* __restrict__ lnw, const float* __restrict__ lnb,
                                              float* __restrict__ out, int row0){
  int mt = blockIdx.x;                                 // 0..399
  int tid = threadIdx.x, lane = tid & 63, wave = tid >> 6;
  int wn = wave*64;
  __shared__ __align__(16) short lA[64*LDS64];
  __shared__ __align__(16) short lB[256*LDS64];
  __shared__ float ssum[64][4], ssq[64][4];
  f32x4 acc[4][4];
  #pragma unroll
  for(int i=0;i<4;i++)
    #pragma unroll
    for(int j=0;j<4;j++) acc[i][j] = (f32x4){0.f,0.f,0.f,0.f};
  const short* Ab = hid + ((size_t)(mt*64))*1024;
  for(int k0=0; k0<1024; k0+=64){
    stage_tile<64>(lA, Ab + k0, 1024, tid);
    stage_tile<256>(lB, fw2t + k0, 1024, tid);
    __syncthreads();
    mma_bk64(lA, lB, 0, wn, lane, acc);
    __syncthreads();
  }
  int m_l = lane & 15, quad = lane >> 4;
  int rowg0 = row0 + mt*64;
  #pragma unroll
  for(int i=0;i<4;i++){
    #pragma unroll
    for(int j=0;j<4;j++){
      int col = wn + j*16 + m_l;
      float bias = fb2[col];
      #pragma unroll
      for(int r=0;r<4;r++){
        int mrow = i*16 + quad*4 + r;
        acc[i][j][r] += bias + hs[(size_t)(rowg0+mrow)*256 + col];
      }
    }
  }
  #pragma unroll
  for(int i=0;i<4;i++){
    #pragma unroll
    for(int r=0;r<4;r++){
      float sv = 0.f, sq = 0.f;
      #pragma unroll
      for(int j=0;j<4;j++){ float v = acc[i][j][r]; sv += v; sq += v*v; }
      #pragma unroll
      for(int msk=1; msk<16; msk<<=1){ sv += __shfl_xor(sv, msk); sq += __shfl_xor(sq, msk); }
      if(m_l == 0){ int mrow = i*16 + quad*4 + r; ssum[mrow][wave] = sv; ssq[mrow][wave] = sq; }
    }
  }
  __syncthreads();
  if(tid < 64){
    float s1 = ssum[tid][0]+ssum[tid][1]+ssum[tid][2]+ssum[tid][3];
    float s2 = ssq[tid][0]+ssq[tid][1]+ssq[tid][2]+ssq[tid][3];
    float mean = s1*(1.f/256.f);
    float var  = s2*(1.f/256.f) - mean*mean;
    ssum[tid][0] = mean;
    ssq[tid][0]  = rsqrtf(var + 1e-12f);
  }
  __syncthreads();
  #pragma unroll
  for(int i=0;i<4;i++){
    #pragma unroll
    for(int j=0;j<4;j++){
      int col = wn + j*16 + m_l;
      float gw = lnw[col], gb = lnb[col];
      #pragma unroll
      for(int r=0;r<4;r++){
        int mrow = i*16 + quad*4 + r;
        float mean = ssum[mrow][0], inv = ssq[mrow][0];
        out[(size_t)(rowg0+mrow)*256 + col] = (acc[i][j][r] - mean)*inv*gw + gb;
      }
    }
  }
}

// =================== launch ===================
extern "C" void kernel_launch(void* const* d_in, const int* in_sizes, int n_in,
                              void* d_out, int out_size, void* d_ws, size_t ws_size,
                              hipStream_t stream){
  const float* inp    = (const float*)d_in[0];
  const float* conv_w = (const float*)d_in[1];
  const float* conv_b = (const float*)d_in[2];
  const float* fm_w1  = (const float*)d_in[3];
  const float* fm_b1  = (const float*)d_in[4];
  const float* fm_w2  = (const float*)d_in[5];
  const float* fm_b2  = (const float*)d_in[6];
  const float* cm_w1  = (const float*)d_in[7];
  const float* cm_b1  = (const float*)d_in[8];
  const float* cm_w2  = (const float*)d_in[9];
  const float* cm_b2  = (const float*)d_in[10];
  const float* sm_w1  = (const float*)d_in[11];
  const float* sm_b1  = (const float*)d_in[12];
  const float* sm_w2  = (const float*)d_in[13];
  const float* sm_b2  = (const float*)d_in[14];
  const float* ln_w   = (const float*)d_in[15];
  const float* ln_b   = (const float*)d_in[16];
  const float* ff_w1  = (const float*)d_in[17];
  const float* ff_b1  = (const float*)d_in[18];
  const float* ff_w2  = (const float*)d_in[19];
  const float* ff_b2  = (const float*)d_in[20];
  const float* ffln_w = (const float*)d_in[21];
  const float* ffln_b = (const float*)d_in[22];
  float* out = (float*)d_out;

  const size_t NS = (size_t)B_ * NSEG_ * FREQ_ * H_;   // 15,335,424
  const size_t HN = (size_t)NSEG_ * 1152 * 1024;       // 30,670,848
  short* ws = (short*)d_ws;
  bf16*  b0   = (bf16*)ws;                  // region A
  bf16*  b1   = (bf16*)(ws + NS);
  bf16*  b2   = (bf16*)(ws + 2*NS);         // region B
  bf16*  b3   = (bf16*)(ws + 3*NS);
  short* H    = ws + 4*NS;                  // 61.3 MB
  short* B1t  = H + HN;                     // 27.3 MB
  short* B2r  = B1t + (size_t)26*1024*512;  // 13.6 MB
  short* B2i  = B2r + (size_t)26*256*1024;  // 6.8 MB
  short* fw1t = B2i + (size_t)26*256*512;   // 0.5 MB
  short* fw2t = fw1t + 262144;              // 0.5 MB
  short* B1sm = fw2t + 262144;              // 147 KB
  short* B2sm = B1sm + 73728;               // 147 KB
  short* B1fm = B2sm + 73728;               // 80 KB
  short* B2fm = B1fm + 39936;               // 104 KB
  float* cwT  = (float*)(B2fm + 53248);     // 240 KB
  float* hs   = (float*)b0;                 // 52.4 MB over region A
  bf16*  hsb  = (bf16*)H;                   // 26.2 MB over H
  short* hid  = (short*)b2;                 // 52.4 MB over region B

  // ---- weight repack (idempotent, every call) ----
  k_prep_b1<<<1664, 256, 0, stream>>>(cm_w1, B1t);
  k_prep_b2<<<832,  256, 0, stream>>>(cm_w2, B2r, B2i);
  k_transp <<<64,   256, 0, stream>>>(ff_w1, fw1t, 256, 1024);
  k_transp <<<64,   256, 0, stream>>>(ff_w2, fw2t, 1024, 256);
  k_prep_sm<<<9,    256, 0, stream>>>(sm_w1, sm_w2, B1sm, B2sm);
  k_prep_fm<<<26,   256, 0, stream>>>(fm_w1, fm_w2, B1fm, B2fm);
  k_prep_cw<<<26,   256, 0, stream>>>(conv_w, cwT);

  // ---- pipeline ----
  k_sfm3<<<B_*NSEG_, 256, 0, stream>>>(inp, cwT, conv_b, B1fm, B2fm, fm_b1, fm_b2, b2, b3);
  for(int half=0; half<2; half++){
    k_cm1<<<26*72, 256, 0, stream>>>(b2, b3, B1t, cm_b1, H, half);
    k_cm2<<<26*36, 256, 0, stream>>>(H, B2r, B2i, cm_b2, b0, b1, half);
  }
  k_smm<<<B_*2*FREQ_, 256, 0, stream>>>(b0, b1, B1sm, B2sm, sm_b1, sm_b2, b2, b3);
  k_ist8<<<B_*25, 256, 0, stream>>>(b2, b3, inp, ln_w, ln_b, hs, hsb);
  for(int c=0; c<2; c++){
    int row0 = c*25600;
    k_ff1m<<<1600, 256, 0, stream>>>((const short*)hsb, fw1t, ff_b1, hid, row0);
    k_ff2m<<<400,  256, 0, stream>>>(hid, fw2t, ff_b2, hs, ffln_w, ffln_b, out, row0);
  }
}

// Round 8
// 839.067 us; speedup vs baseline: 1.0668x; 1.0668x over previous
//
#include <hip/hip_runtime.h>
#include <hip/hip_bf16.h>
#include <math.h>

typedef __hip_bfloat16 bf16;
typedef short bf16x8 __attribute__((ext_vector_type(8)));
typedef float f32x4 __attribute__((ext_vector_type(4)));

#define B_    256
#define SEQ_  200
#define H_    256
#define FREQ_ 9
#define NSEG_ 26
#define LDS64 64   // linear LDS rows (64 shorts = 128 B); bank spread via XOR swizzle

__device__ __forceinline__ float ldb(const bf16* p, size_t i){ return __bfloat162float(p[i]); }
__device__ __forceinline__ void stb(bf16* p, size_t i, float v){ p[i] = __float2bfloat16(v); }
__device__ __forceinline__ short f2b(float v){ union{bf16 b; short s;} c; c.b = __float2bfloat16(v); return c.s; }
__device__ __forceinline__ unsigned short f2bu(float v){ union{bf16 b; unsigned short s;} c; c.b = __float2bfloat16(v); return c.s; }
// tanh-form gelu (max dev vs erf-form ~3.7e-4, far below bf16 activation quantization).
__device__ __forceinline__ float gelu_(float x){
  float y  = 0.7978845608f*(x + 0.044715f*x*x*x);
  float ay = fabsf(y);
  float e  = __expf(-2.f*ay);
  float th = 1.f - 2.f*e*__builtin_amdgcn_rcpf(1.f + e);
  th = copysignf(th, y);
  return 0.5f*x*(1.f + th);
}

__device__ __constant__ float CT16[16] = {
  1.0f, 0.9238795325f, 0.7071067812f, 0.3826834324f, 0.0f, -0.3826834324f, -0.7071067812f, -0.9238795325f,
 -1.0f,-0.9238795325f,-0.7071067812f,-0.3826834324f, 0.0f,  0.3826834324f, 0.7071067812f,  0.9238795325f};
__device__ __constant__ float ST16[16] = {
  0.0f, 0.3826834324f, 0.7071067812f, 0.9238795325f, 1.0f,  0.9238795325f, 0.7071067812f,  0.3826834324f,
  0.0f,-0.3826834324f,-0.7071067812f,-0.9238795325f,-1.0f, -0.9238795325f,-0.7071067812f, -0.3826834324f};

// =================== shared MFMA GEMM machinery ===================
__device__ __forceinline__ void gload16(const short* g, short* l){
  __builtin_amdgcn_global_load_lds(
      (const __attribute__((address_space(1))) unsigned int*)(const void*)g,
      (__attribute__((address_space(3))) unsigned int*)(void*)l, 16, 0, 0);
}

// stage ROWS x 64 bf16 tile from global [row][k] (k-contiguous) into LDS [ROWS][64]
template<int ROWS>
__device__ __forceinline__ void stage_tile(short* lds, const short* src, int rstride, int tid){
  int rl = tid >> 3;        // row within 32-row group
  int c  = tid & 7;         // 16B chunk slot (linear in LDS)
  #pragma unroll
  for(int p=0; p<ROWS/32; p++){
    int r = p*32 + rl;
    int csrc = c ^ (r & 7); // inverse swizzle on the global side
    gload16(src + (size_t)r*rstride + csrc*8, lds + r*LDS64 + c*8);
  }
}

// one BK=64 step: wave computes 64x64 via 4x4 grid of 16x16x32 MFMA
__device__ __forceinline__ void mma_bk64(const short* lA, const short* lB, int wm, int wn,
                                         int lane, f32x4 acc[4][4]){
  int m_l = lane & 15, quad = lane >> 4;
  int sw = m_l & 7;
  #pragma unroll
  for(int ks=0; ks<64; ks+=32){
    int cs = (((ks>>3) + quad) ^ sw) * 8;
    bf16x8 a[4], b[4];
    #pragma unroll
    for(int i=0;i<4;i++) a[i] = *(const bf16x8*)&lA[(wm + i*16 + m_l)*LDS64 + cs];
    #pragma unroll
    for(int j=0;j<4;j++) b[j] = *(const bf16x8*)&lB[(wn + j*16 + m_l)*LDS64 + cs];
    #pragma unroll
    for(int i=0;i<4;i++)
      #pragma unroll
      for(int j=0;j<4;j++)
        acc[i][j] = __builtin_amdgcn_mfma_f32_16x16x32_bf16(a[i], b[j], acc[i][j], 0,0,0);
  }
}

// =================== prep: weight repack (fp32 -> transposed bf16) ===================
__global__ __launch_bounds__(256) void k_prep_b1(const float* __restrict__ w1, short* __restrict__ B1t){
  int g = blockIdx.x;
  int jt = g & 7, ht = (g>>3)&3, p = (g>>5)&1, s = g>>6;   // 26*64 = 1664 blocks
  __shared__ float tile[64][65];
  int t = threadIdx.x;
  const float* src = w1 + (size_t)p*3407872 + (size_t)s*131072;
  #pragma unroll
  for(int q=0;q<16;q++){
    int r = q*4 + (t>>6), c = t & 63;
    tile[r][c] = src[(size_t)(ht*64 + r)*512 + jt*64 + c];   // W1p[h][j]
  }
  __syncthreads();
  int n_l = t >> 2, kc = (t & 3)*16;
  short tA[16] __attribute__((aligned(16)));
  short tB[16] __attribute__((aligned(16)));
  #pragma unroll
  for(int i=0;i<16;i++){
    float v = tile[kc+i][n_l];
    tA[i] = (p==0) ? f2b(v) : f2b(-v);
    tB[i] = f2b(v);
  }
  int j = jt*64 + n_l, h = ht*64 + kc;
  size_t d1, d2;
  if(p==0){ d1 = ((size_t)(s*1024 + j))*512 + h;
            d2 = ((size_t)(s*1024 + 512 + j))*512 + 256 + h; }
  else    { d1 = ((size_t)(s*1024 + j))*512 + 256 + h;
            d2 = ((size_t)(s*1024 + 512 + j))*512 + h; }
  *(int4*)&B1t[d1] = *(int4*)&tA[0]; *(int4*)&B1t[d1+8] = *(int4*)&tA[8];
  *(int4*)&B1t[d2] = *(int4*)&tB[0]; *(int4*)&B1t[d2+8] = *(int4*)&tB[8];
}

__global__ __launch_bounds__(256) void k_prep_b2(const float* __restrict__ w2,
                                                 short* __restrict__ B2r, short* __restrict__ B2i){
  int g = blockIdx.x;
  int ht = g & 3, jt = (g>>2)&7, s = g>>5;                  // 26*32 = 832 blocks
  __shared__ float t0[64][65], t1[64][65];
  int t = threadIdx.x;
  const float* s0 = w2 + (size_t)s*131072;
  const float* s1 = w2 + 3407872 + (size_t)s*131072;
  #pragma unroll
  for(int q=0;q<16;q++){
    int r = q*4 + (t>>6), c = t & 63;
    t0[r][c] = s0[(size_t)(jt*64 + r)*256 + ht*64 + c];
    t1[r][c] = s1[(size_t)(jt*64 + r)*256 + ht*64 + c];
  }
  __syncthreads();
  int n_l = t >> 2, jc = (t & 3)*16;
  short ta[16] __attribute__((aligned(16)));
  short tb[16] __attribute__((aligned(16)));
  short tc[16] __attribute__((aligned(16)));
  #pragma unroll
  for(int i=0;i<16;i++){
    float v0 = t0[jc+i][n_l], v1 = t1[jc+i][n_l];
    ta[i] = f2b(v0); tb[i] = f2b(-v1); tc[i] = f2b(v0+v1);
  }
  int n = ht*64 + n_l, j = jt*64 + jc;
  size_t dr = ((size_t)(s*256 + n))*1024 + j;
  size_t di = ((size_t)(s*256 + n))*512 + j;
  *(int4*)&B2r[dr]     = *(int4*)&ta[0]; *(int4*)&B2r[dr+8]     = *(int4*)&ta[8];
  *(int4*)&B2r[dr+512] = *(int4*)&tb[0]; *(int4*)&B2r[dr+520]   = *(int4*)&tb[8];
  *(int4*)&B2i[di]     = *(int4*)&tc[0]; *(int4*)&B2i[di+8]     = *(int4*)&tc[8];
}

// generic transpose fp32 [R][C] -> bf16 [C][R]
__global__ __launch_bounds__(256) void k_transp(const float* __restrict__ src, short* __restrict__ dst,
                                                int R, int C){
  int ct = blockIdx.x % (C/64);
  int rt = blockIdx.x / (C/64);
  __shared__ float tile[64][65];
  int t = threadIdx.x;
  #pragma unroll
  for(int p=0;p<16;p++){
    int r = p*4 + (t>>6), c = t & 63;
    tile[r][c] = src[(size_t)(rt*64 + r)*C + ct*64 + c];
  }
  __syncthreads();
  int row_out = t >> 2, rc = (t & 3)*16;
  short tmp[16] __attribute__((aligned(16)));
  #pragma unroll
  for(int i=0;i<16;i++) tmp[i] = f2b(tile[rc+i][row_out]);
  size_t base = (size_t)(ct*64 + row_out)*R + rt*64 + rc;
  *(int4*)&dst[base] = *(int4*)&tmp[0]; *(int4*)&dst[base+8] = *(int4*)&tmp[8];
}

// prep for MFMA segment mixer
__global__ __launch_bounds__(256) void k_prep_sm(const float* __restrict__ w1, const float* __restrict__ w2,
                                                 short* __restrict__ B1sm, short* __restrict__ B2sm){
  int f = blockIdx.x;  // 9 blocks
  int t = threadIdx.x;
  for(int idx=t; idx<8192; idx+=256){
    int jp = idx >> 6, k = idx & 63;
    float v = 0.f;
    if(jp < 104){
      int j = (jp < 52) ? jp : jp - 52;
      if(k < 26){
        int s = k;
        v = (jp < 52) ? w1[f*1352 + s*52 + j] : w1[12168 + f*1352 + s*52 + j];
      } else if(k >= 32 && k < 58){
        int s = k - 32;
        v = (jp < 52) ? -w1[12168 + f*1352 + s*52 + j] : w1[f*1352 + s*52 + j];
      }
    }
    B1sm[(size_t)f*8192 + idx] = f2b(v);
  }
  for(int idx=t; idx<8192; idx+=256){
    int sop = idx >> 7, k = idx & 127;
    float v = 0.f;
    if(sop < 26){
      if(k < 52)       v = w2[f*1352 + k*26 + sop];
      else if(k < 104) v = -w2[12168 + f*1352 + (k-52)*26 + sop];
    } else if(sop < 52){
      int so = sop - 26;
      if(k >= 52 && k < 104)
        v = w2[f*1352 + (k-52)*26 + so] + w2[12168 + f*1352 + (k-52)*26 + so];
    }
    B2sm[(size_t)f*8192 + idx] = f2b(v);
  }
}

// prep for MFMA frequency mixer
__global__ __launch_bounds__(256) void k_prep_fm(const float* __restrict__ w1, const float* __restrict__ w2,
                                                 short* __restrict__ B1fm, short* __restrict__ B2fm){
  int s = blockIdx.x;  // 26 blocks
  int t = threadIdx.x;
  for(int idx=t; idx<1536; idx+=256){
    int n = idx >> 5, k = idx & 31;
    float v = 0.f;
    if(n < 18){
      if(k < 9)       v = w1[s*162 + k*18 + n];
      else if(k < 18) v = -w1[4212 + s*162 + (k-9)*18 + n];
    } else if(n < 36){
      int j = n - 18;
      if(k < 9)       v = w1[4212 + s*162 + k*18 + j];
      else if(k < 18) v = w1[s*162 + (k-9)*18 + j];
    }
    B1fm[s*1536 + idx] = f2b(v);
  }
  for(int idx=t; idx<2048; idx+=256){
    int n = idx >> 6, k = idx & 63;
    float v = 0.f;
    if(n < 9){
      if(k < 18)      v = w2[s*162 + k*9 + n];
      else if(k < 36) v = -w2[4212 + s*162 + (k-18)*9 + n];
    } else if(n < 18){
      int f = n - 9;
      if(k >= 18 && k < 36)
        v = w2[s*162 + (k-18)*9 + f] + w2[4212 + s*162 + (k-18)*9 + f];
    }
    B2fm[s*2048 + idx] = f2b(v);
  }
}

// transpose conv_w [s][h][f] -> cwT [s][f][h] so the gating gather is coalesced
__global__ __launch_bounds__(256) void k_prep_cw(const float* __restrict__ cw, float* __restrict__ cwT){
  int s = blockIdx.x; int t = threadIdx.x;  // 26 blocks
  __shared__ float tile[2304];
  for(int i=t; i<2304; i+=256) tile[i] = cw[s*2304 + i];
  __syncthreads();
  #pragma unroll
  for(int f=0; f<9; f++) cwT[(s*9+f)*256 + t] = tile[t*9+f];
}

// =================== Kernel 1: fused STFT + gating + frequency mixer (MFMA mixer) ===================
// (round-6 structure: register DFT, no extra barriers; only the gating reduce is
// shuffle-based now — 1 barrier instead of 8)
#define LX1 40
#define LG1 72
__global__ __launch_bounds__(256) void k_sfm2(const float* __restrict__ inp,
                                              const float* __restrict__ cwT, const float* __restrict__ cb,
                                              const short* __restrict__ B1fm, const short* __restrict__ B2fm,
                                              const float* __restrict__ bb1, const float* __restrict__ bb2,
                                              bf16* __restrict__ oR, bf16* __restrict__ oI){
  int blk = blockIdx.x; int b = blk / NSEG_; int s = blk % NSEG_; int t = threadIdx.x;
  int lane = t & 63, wave = t >> 6, m_l = lane & 15, quad = lane >> 4;
  __shared__ __align__(16) short sm[20736];   // 41.5 KB
  __shared__ float wred[4];
  __shared__ float lb1f[48];
  short* lX  = sm;            // [256][LX1] phase 1
  short* lB1 = sm + 10240;    // [48][LX1]  phase 1 (dead after L1)
  short* lG  = sm;            // [256][LG1] phase 2 overlay
  short* lB2 = sm + 18432;    // [32][LG1]  persistent

  // ---- stage packed mixer weights + bias for this s ----
  {
    const short* src1 = B1fm + s*1536;
    for(int idx=t; idx<768; idx+=256){            // 48 rows x 16 u32
      int r = idx >> 4, c = idx & 15;
      *(unsigned*)&lB1[r*LX1 + c*2] = *(const unsigned*)&src1[r*32 + c*2];
    }
    const short* src2 = B2fm + s*2048;
    for(int idx=t; idx<1024; idx+=256){           // 32 rows x 32 u32
      int r = idx >> 5, c = idx & 31;
      *(unsigned*)&lB2[r*LG1 + c*2] = *(const unsigned*)&src2[r*64 + c*2];
    }
    if(t < 48) lb1f[t] = (t < 18) ? bb1[s*18 + t] : (t < 36 ? bb1[468 + s*18 + (t-18)] : 0.f);
  }

  // ---- gating weights: 9 coalesced loads (cwT layout) ----
  float cwv[9];
  #pragma unroll
  for(int f=0;f<9;f++) cwv[f] = cwT[(s*9+f)*256 + t];

  // ---- STFT (16-point real DFT, 9 bins) ----
  float xv[16];
  int t0 = s*8 - 8;
  #pragma unroll
  for(int k=0;k<16;k++){
    int tt = t0 + k;
    xv[k] = (tt>=0 && tt<SEQ_) ? inp[(size_t)(b*SEQ_+tt)*H_ + t] : 0.0f;
  }
  float xr[9], xi[9];
  float acc = 0.f;
  #pragma unroll
  for(int f=0;f<FREQ_;f++){
    float ar=0.f, ai=0.f;
    #pragma unroll
    for(int k=0;k<16;k++){
      int m = (f*k) & 15;
      ar += xv[k]*CT16[m];
      ai -= xv[k]*ST16[m];
    }
    xr[f] = 0.25f*ar; xi[f] = 0.25f*ai;
    acc += sqrtf(xr[f]*xr[f] + xi[f]*xi[f]) * cwv[f];
  }

  // ---- gating weight: shuffle-reduce over 64 lanes + 4-entry LDS combine ----
  #pragma unroll
  for(int msk=1; msk<64; msk<<=1) acc += __shfl_xor(acc, msk);
  if(lane == 0) wred[wave] = acc;
  __syncthreads();
  float wv = wred[0]+wred[1]+wred[2]+wred[3] + cb[s] + __expf((float)(s - (NSEG_-1)));

  // ---- write lX[t][k] as 4 x b128: k<9 xr*wv, 9..17 xi*wv, 18..31 zero ----
  {
    float vb[32];
    #pragma unroll
    for(int f=0;f<9;f++){ vb[f] = xr[f]*wv; vb[9+f] = xi[f]*wv; }
    #pragma unroll
    for(int k=18;k<32;k++) vb[k] = 0.f;
    union { unsigned u[16]; int4 v4[4]; } pk;
    #pragma unroll
    for(int c=0;c<16;c++)
      pk.u[c] = (unsigned)f2bu(vb[2*c]) | ((unsigned)f2bu(vb[2*c+1]) << 16);
    #pragma unroll
    for(int q=0;q<4;q++) *(int4*)&lX[t*LX1 + q*8] = pk.v4[q];   // 80B row stride: 16-aligned
  }
  __syncthreads();

  // ---- layer1 MFMA: wave strip 64 h-rows, N=48, K=32 ----
  int h0 = wave*64;
  f32x4 acc1[4][3];
  #pragma unroll
  for(int i=0;i<4;i++)
    #pragma unroll
    for(int j=0;j<3;j++) acc1[i][j] = (f32x4){0.f,0.f,0.f,0.f};
  {
    bf16x8 a1[4], b1v[3];
    #pragma unroll
    for(int i=0;i<4;i++) a1[i] = *(const bf16x8*)&lX[(h0 + i*16 + m_l)*LX1 + quad*8];
    #pragma unroll
    for(int j=0;j<3;j++) b1v[j] = *(const bf16x8*)&lB1[(j*16 + m_l)*LX1 + quad*8];
    #pragma unroll
    for(int i=0;i<4;i++)
      #pragma unroll
      for(int j=0;j<3;j++)
        acc1[i][j] = __builtin_amdgcn_mfma_f32_16x16x32_bf16(a1[i], b1v[j], acc1[i][j], 0,0,0);
  }
  __syncthreads();   // lX/lB1 reads done before lG overlay

  // ---- gelu + bias -> lG (n in 36..47 land exactly 0: zero B rows + zero bias) ----
  #pragma unroll
  for(int i=0;i<4;i++){
    #pragma unroll
    for(int j=0;j<3;j++){
      int n = j*16 + m_l;
      float bias = lb1f[n];
      #pragma unroll
      for(int r=0;r<4;r++){
        int row = h0 + i*16 + quad*4 + r;
        lG[row*LG1 + n] = f2b(gelu_(acc1[i][j][r] + bias));
      }
    }
  }
  // zero pad cols 48..63 of own row (K2=64; must not be NaN-garbage)
  #pragma unroll
  for(int c=0;c<8;c++) *(unsigned*)&lG[t*LG1 + 48 + c*2] = 0u;
  __syncthreads();

  // ---- layer2 MFMA: N=32 (18 used), K=64 ----
  f32x4 acc2[4][2];
  #pragma unroll
  for(int i=0;i<4;i++)
    #pragma unroll
    for(int j=0;j<2;j++) acc2[i][j] = (f32x4){0.f,0.f,0.f,0.f};
  #pragma unroll
  for(int ks=0; ks<64; ks+=32){
    bf16x8 a2[4], b2v[2];
    #pragma unroll
    for(int i=0;i<4;i++) a2[i] = *(const bf16x8*)&lG[(h0 + i*16 + m_l)*LG1 + ks + quad*8];
    #pragma unroll
    for(int j=0;j<2;j++) b2v[j] = *(const bf16x8*)&lB2[(j*16 + m_l)*LG1 + ks + quad*8];
    #pragma unroll
    for(int i=0;i<4;i++)
      #pragma unroll
      for(int j=0;j<2;j++)
        acc2[i][j] = __builtin_amdgcn_mfma_f32_16x16x32_bf16(a2[i], b2v[j], acc2[i][j], 0,0,0);
  }

  // ---- epilogue: +b2, write oR (n<9) / oI (9<=n<18), 4 consecutive h packed ----
  #pragma unroll
  for(int j=0;j<2;j++){
    int n = j*16 + m_l;
    if(n < 18){
      bool isI = n >= 9;
      int f = isI ? n-9 : n;
      float bias = isI ? bb2[234 + s*9 + f] : bb2[s*9 + f];
      bf16* outp = isI ? oI : oR;
      size_t base = ((size_t)(s*B_ + b)*FREQ_ + f)*H_;
      #pragma unroll
      for(int i=0;i<4;i++){
        int h = h0 + i*16 + quad*4;
        short pk[4] __attribute__((aligned(8)));
        #pragma unroll
        for(int r=0;r<4;r++) pk[r] = f2b(acc2[i][j][r] + bias);
        *(int2*)&outp[base + h] = *(const int2*)&pk[0];
      }
    }
  }
}

// =================== Kernel 4a: channel mixer layer1 (MFMA) ===================
__global__ __launch_bounds__(256) void k_cm1(const bf16* __restrict__ Xr, const bf16* __restrict__ Xi,
                                             const short* __restrict__ B1t, const float* __restrict__ b1bias,
                                             short* __restrict__ H, int half){
  int nt = blockIdx.x & 7, mt = (blockIdx.x >> 3) % 9, s = blockIdx.x / 72;
  int tid = threadIdx.x, lane = tid & 63, wave = tid >> 6;
  int wm = (wave & 1)*64, wn = (wave >> 1)*64;
  __shared__ __align__(16) short lA[128*LDS64];
  __shared__ __align__(16) short lB[128*LDS64];
  f32x4 acc[4][4];
  #pragma unroll
  for(int i=0;i<4;i++)
    #pragma unroll
    for(int j=0;j<4;j++) acc[i][j] = (f32x4){0.f,0.f,0.f,0.f};
  int rowbase = half*1152 + mt*128;
  const short* Bbase = B1t + ((size_t)(s*1024 + nt*128))*512;
  for(int k0=0; k0<512; k0+=64){
    const short* Asrc = (k0 < 256)
      ? (const short*)(Xr + ((size_t)(s*2304 + rowbase))*256 + k0)
      : (const short*)(Xi + ((size_t)(s*2304 + rowbase))*256 + (k0-256));
    stage_tile<128>(lA, Asrc, 256, tid);
    stage_tile<128>(lB, Bbase + k0, 512, tid);
    __syncthreads();
    mma_bk64(lA, lB, wm, wn, lane, acc);
    __syncthreads();
  }
  int m_l = lane & 15, quad = lane >> 4;
  #pragma unroll
  for(int i=0;i<4;i++){
    #pragma unroll
    for(int j=0;j<4;j++){
      int n = nt*128 + wn + j*16 + m_l;
      float bias = (n < 512) ? b1bias[s*512 + n] : b1bias[13312 + s*512 + (n-512)];
      #pragma unroll
      for(int r=0;r<4;r++){
        int mrow = wm + i*16 + quad*4 + r;
        float v = gelu_(acc[i][j][r] + bias);
        H[((size_t)(s*1152 + mt*128 + mrow))*1024 + n] = f2b(v);
      }
    }
  }
}

// =================== Kernel 4b: channel mixer layer2 (MFMA) ===================
__global__ __launch_bounds__(256) void k_cm2(const short* __restrict__ H,
                                             const short* __restrict__ B2r, const short* __restrict__ B2i,
                                             const float* __restrict__ b2bias,
                                             bf16* __restrict__ oR, bf16* __restrict__ oI, int half){
  int nt = blockIdx.x & 3, mt = (blockIdx.x>>2) % 9, s = blockIdx.x / 36;
  int tid = threadIdx.x, lane = tid & 63, wave = tid >> 6;
  int wm = (wave & 1)*64, wn = (wave >> 1)*64;
  bool isOi = nt >= 2;
  int n0 = (nt & 1)*128;
  int K = isOi ? 512 : 1024;
  int Aoff = isOi ? 512 : 0;
  int Bstride = isOi ? 512 : 1024;
  const short* Bb = isOi ? (B2i + ((size_t)(s*256 + n0))*512) : (B2r + ((size_t)(s*256 + n0))*1024);
  const short* Ab = H + ((size_t)(s*1152 + mt*128))*1024 + Aoff;
  __shared__ __align__(16) short lA[128*LDS64];
  __shared__ __align__(16) short lB[128*LDS64];
  f32x4 acc[4][4];
  #pragma unroll
  for(int i=0;i<4;i++)
    #pragma unroll
    for(int j=0;j<4;j++) acc[i][j] = (f32x4){0.f,0.f,0.f,0.f};
  for(int k0=0; k0<K; k0+=64){
    stage_tile<128>(lA, Ab + k0, 1024, tid);
    stage_tile<128>(lB, Bb + k0, Bstride, tid);
    __syncthreads();
    mma_bk64(lA, lB, wm, wn, lane, acc);
    __syncthreads();
  }
  int m_l = lane & 15, quad = lane >> 4;
  bf16* outp = isOi ? oI : oR;
  #pragma unroll
  for(int i=0;i<4;i++){
    #pragma unroll
    for(int j=0;j<4;j++){
      int n = n0 + wn + j*16 + m_l;
      float bias = b2bias[(isOi ? 6656 : 0) + s*256 + n];
      #pragma unroll
      for(int r=0;r<4;r++){
        int mrow = wm + i*16 + quad*4 + r;
        int rowg = half*1152 + mt*128 + mrow;
        stb(outp, ((size_t)rowg*NSEG_ + s)*256 + n, acc[i][j][r] + bias);
      }
    }
  }
}

// =================== Kernel 5: segment mixer (MFMA, 8-wave for occupancy) ===================
// 512 threads: 8 waves x 16 h-rows. Same 54.3 KB LDS (2 blocks/CU) but 16 waves/CU
// resident instead of 8 -> latency hiding for the short MFMA bursts + 5-barrier chain.
#define LDX 72
#define LDG 136
__global__ __launch_bounds__(512) void k_smm(const bf16* __restrict__ iR, const bf16* __restrict__ iI,
                                             const short* __restrict__ B1sm, const short* __restrict__ B2sm,
                                             const float* __restrict__ bb1, const float* __restrict__ bb2,
                                             bf16* __restrict__ oR, bf16* __restrict__ oI){
  int blk = blockIdx.x;
  int f  = blk % 9;
  int hh = (blk/9) & 1;
  int bq = blk / 18;
  int t = threadIdx.x, lane = t & 63, wave = t >> 6;   // 8 waves
  int m_l = lane & 15, quad = lane >> 4;
  __shared__ __align__(16) short sm[18432 + 8704];  // 54.3 KB
  __shared__ float lb1[128];
  short* lX  = sm;                 // [128][LDX]
  short* lB1 = sm + 128*LDX;       // [128][LDX]
  short* lG  = sm;                 // [128][LDG] overlay (after barrier)
  short* lB2 = sm + 18432;         // [64][LDG]
  int rbase = (bq*9 + f)*26;

  #pragma unroll
  for(int it=0; it<2; it++){
    int idx = it*512 + t;          // 1024 x 16B
    int r = idx >> 3, c = idx & 7;
    *(int4*)&lB1[r*LDX + c*8] = *(const int4*)&B1sm[(size_t)f*8192 + r*64 + c*8];
  }
  #pragma unroll
  for(int it=0; it<2; it++){
    int idx = it*512 + t;
    int r = idx >> 4, c = idx & 15;
    *(int4*)&lB2[r*LDG + c*8] = *(const int4*)&B2sm[(size_t)f*8192 + r*128 + c*8];
  }
  if(t < 128) lb1[t] = (t < 52) ? bb1[f*52 + t] : (t < 104 ? bb1[468 + f*52 + (t-52)] : 0.f);

  int hl = t & 127, g = t >> 7;    // g in 0..3
  #pragma unroll
  for(int it=0; it<7; it++){
    int a = it*4 + g;              // 26 tasks over 4 groups
    if(a < 26){
      int arr = a >= 13;
      int pr  = arr ? a-13 : a;
      int s0  = pr*2;
      const bf16* src = arr ? iI : iR;
      unsigned v0 = *(const unsigned short*)&src[((size_t)(rbase+s0  ))*256 + hh*128 + hl];
      unsigned v1 = *(const unsigned short*)&src[((size_t)(rbase+s0+1))*256 + hh*128 + hl];
      *(unsigned*)&lX[hl*LDX + arr*32 + s0] = v0 | (v1 << 16);
    }
  }
  if(g < 2){
    int zb = g ? 58 : 26;
    #pragma unroll
    for(int i=0;i<3;i++) *(unsigned*)&lX[hl*LDX + zb + i*2] = 0u;
  }
  __syncthreads();

  int h0 = wave*16;
  f32x4 acc1[8];
  #pragma unroll
  for(int j=0;j<8;j++) acc1[j] = (f32x4){0.f,0.f,0.f,0.f};
  #pragma unroll
  for(int ks=0; ks<64; ks+=32){
    bf16x8 av, bv[8];
    av = *(const bf16x8*)&lX[(h0 + m_l)*LDX + ks + quad*8];
    #pragma unroll
    for(int j=0;j<8;j++) bv[j] = *(const bf16x8*)&lB1[(j*16 + m_l)*LDX + ks + quad*8];
    #pragma unroll
    for(int j=0;j<8;j++)
      acc1[j] = __builtin_amdgcn_mfma_f32_16x16x32_bf16(av, bv[j], acc1[j], 0,0,0);
  }
  __syncthreads();

  #pragma unroll
  for(int j=0;j<8;j++){
    int jp = j*16 + m_l;
    float bias = lb1[jp];
    #pragma unroll
    for(int r=0;r<4;r++){
      int hrow = h0 + quad*4 + r;
      lG[hrow*LDG + jp] = f2b(gelu_(acc1[j][r] + bias));
    }
  }
  __syncthreads();

  f32x4 acc2[4];
  #pragma unroll
  for(int j=0;j<4;j++) acc2[j] = (f32x4){0.f,0.f,0.f,0.f};
  #pragma unroll
  for(int ks=0; ks<128; ks+=32){
    bf16x8 av, bv[4];
    av = *(const bf16x8*)&lG[(h0 + m_l)*LDG + ks + quad*8];
    #pragma unroll
    for(int j=0;j<4;j++) bv[j] = *(const bf16x8*)&lB2[(j*16 + m_l)*LDG + ks + quad*8];
    #pragma unroll
    for(int j=0;j<4;j++)
      acc2[j] = __builtin_amdgcn_mfma_f32_16x16x32_bf16(av, bv[j], acc2[j], 0,0,0);
  }

  #pragma unroll
  for(int j=0;j<4;j++){
    int sop = j*16 + m_l;
    if(sop < 52){
      int arr = sop >= 26;
      int so  = sop - (arr ? 26 : 0);
      float bias = bb2[(arr ? 234 : 0) + f*26 + so];
      bf16* outp = arr ? oI : oR;
      int h = hh*128 + h0 + quad*4;
      short pk[4] __attribute__((aligned(8)));
      #pragma unroll
      for(int r=0;r<4;r++) pk[r] = f2b(acc2[j][r] + bias);
      *(int2*)&outp[((size_t)(rbase + so))*256 + h] = *(const int2*)&pk[0];
    }
  }
}

// =================== Kernel 6: iSTFT + residual + LayerNorm (octet-fused) ===================
__global__ __launch_bounds__(256) void k_ist8(const bf16* __restrict__ iR, const bf16* __restrict__ iI,
                                              const float* __restrict__ inp,
                                              const float* __restrict__ lnw, const float* __restrict__ lnb,
                                              float* __restrict__ hs, bf16* __restrict__ hsb){
  int blk = blockIdx.x; int b = blk / 25; int o = blk % 25; int h = threadIdx.x;
  int lane = h & 63, wave = h >> 6;
  float rr[2][9], ii[2][8];
  #pragma unroll
  for(int p=0;p<2;p++){
    int s = o + p;
    size_t base = (size_t)b*FREQ_*NSEG_ + s;
    #pragma unroll
    for(int f=0;f<9;f++) rr[p][f] = ldb(iR, (base + f*NSEG_)*256 + h);
    #pragma unroll
    for(int f=1;f<8;f++) ii[p][f] = ldb(iI, (base + f*NSEG_)*256 + h);
  }
  float z[8];
  #pragma unroll
  for(int dt=0; dt<8; dt++){
    float v  = rr[0][0] + rr[1][0];
    float s8 = rr[0][8] + rr[1][8];
    v += (dt & 1) ? -s8 : s8;
    #pragma unroll
    for(int f=1;f<8;f++){
      int m1 = (f*(dt+8)) & 15;
      int m2 = (f*dt) & 15;
      v += 2.f*(rr[0][f]*CT16[m1] - ii[0][f]*ST16[m1]);
      v += 2.f*(rr[1][f]*CT16[m2] - ii[1][f]*ST16[m2]);
    }
    int t = o*8 + dt;
    z[dt] = 0.125f*v + inp[(size_t)(b*SEQ_+t)*H_ + h];
  }
  __shared__ float wsum[8][4], wsq[8][4];
  #pragma unroll
  for(int dt=0; dt<8; dt++){
    float sv = z[dt], sq = z[dt]*z[dt];
    #pragma unroll
    for(int msk=1; msk<64; msk<<=1){ sv += __shfl_xor(sv, msk); sq += __shfl_xor(sq, msk); }
    if(lane == 0){ wsum[dt][wave] = sv; wsq[dt][wave] = sq; }
  }
  __syncthreads();
  float gw = lnw[h], gb = lnb[h];
  #pragma unroll
  for(int dt=0; dt<8; dt++){
    float s1 = wsum[dt][0]+wsum[dt][1]+wsum[dt][2]+wsum[dt][3];
    float s2 = wsq[dt][0]+wsq[dt][1]+wsq[dt][2]+wsq[dt][3];
    float mean = s1*(1.f/256.f);
    float var  = s2*(1.f/256.f) - mean*mean;
    float inv  = rsqrtf(var + 1e-12f);
    float ov = gw*(z[dt]-mean)*inv + gb;
    int t = o*8 + dt;
    size_t oi = (size_t)(b*SEQ_+t)*H_ + h;
    hs[oi] = ov;
    stb(hsb, oi, ov);
  }
}

// =================== Kernel 7: FFN layer1 (MFMA, 256->1024, gelu) ===================
__global__ __launch_bounds__(256) void k_ff1m(const short* __restrict__ hsb, const short* __restrict__ fw1t,
                                              const float* __restrict__ fb1, short* __restrict__ hid, int row0){
  int nt = blockIdx.x & 7, mt = blockIdx.x >> 3;      // mt 0..199
  int tid = threadIdx.x, lane = tid & 63, wave = tid >> 6;
  int wm = (wave & 1)*64, wn = (wave >> 1)*64;
  __shared__ __align__(16) short lA[128*LDS64];
  __shared__ __align__(16) short lB[128*LDS64];
  f32x4 acc[4][4];
  #pragma unroll
  for(int i=0;i<4;i++)
    #pragma unroll
    for(int j=0;j<4;j++) acc[i][j] = (f32x4){0.f,0.f,0.f,0.f};
  const short* Ab = hsb + ((size_t)(row0 + mt*128))*256;
  const short* Bb = fw1t + ((size_t)(nt*128))*256;
  for(int k0=0; k0<256; k0+=64){
    stage_tile<128>(lA, Ab + k0, 256, tid);
    stage_tile<128>(lB, Bb + k0, 256, tid);
    __syncthreads();
    mma_bk64(lA, lB, wm, wn, lane, acc);
    __syncthreads();
  }
  int m_l = lane & 15, quad = lane >> 4;
  #pragma unroll
  for(int i=0;i<4;i++){
    #pragma unroll
    for(int j=0;j<4;j++){
      int n = nt*128 + wn + j*16 + m_l;
      float bias = fb1[n];
      #pragma unroll
      for(int r=0;r<4;r++){
        int mrow = wm + i*16 + quad*4 + r;
        hid[((size_t)(mt*128 + mrow))*1024 + n] = f2b(gelu_(acc[i][j][r] + bias));
      }
    }
  }
}

// =================== Kernel 8: FFN layer2 (MFMA) + residual + LayerNorm ===================
__global__ __launch_bounds__(256) void k_ff2m(const short* __restrict__ hid, const short* __restrict__ fw2t,
                                              const float* __restrict__ fb2, const float* __restrict__ hs,
                                              const float* __restrict__ lnw, const float* __restrict__ lnb,
                                              float* __restrict__ out, int row0){
  int mt = blockIdx.x;                                 // 0..399
  int tid = threadIdx.x, lane = tid & 63, wave = tid >> 6;
  int wn = wave*64;
  __shared__ __align__(16) short lA[64*LDS64];
  __shared__ __align__(16) short lB[256*LDS64];
  __shared__ float ssum[64][4], ssq[64][4];
  f32x4 acc[4][4];
  #pragma unroll
  for(int i=0;i<4;i++)
    #pragma unroll
    for(int j=0;j<4;j++) acc[i][j] = (f32x4){0.f,0.f,0.f,0.f};
  const short* Ab = hid + ((size_t)(mt*64))*1024;
  for(int k0=0; k0<1024; k0+=64){
    stage_tile<64>(lA, Ab + k0, 1024, tid);
    stage_tile<256>(lB, fw2t + k0, 1024, tid);
    __syncthreads();
    mma_bk64(lA, lB, 0, wn, lane, acc);
    __syncthreads();
  }
  int m_l = lane & 15, quad = lane >> 4;
  int rowg0 = row0 + mt*64;
  #pragma unroll
  for(int i=0;i<4;i++){
    #pragma unroll
    for(int j=0;j<4;j++){
      int col = wn + j*16 + m_l;
      float bias = fb2[col];
      #pragma unroll
      for(int r=0;r<4;r++){
        int mrow = i*16 + quad*4 + r;
        acc[i][j][r] += bias + hs[(size_t)(rowg0+mrow)*256 + col];
      }
    }
  }
  #pragma unroll
  for(int i=0;i<4;i++){
    #pragma unroll
    for(int r=0;r<4;r++){
      float sv = 0.f, sq = 0.f;
      #pragma unroll
      for(int j=0;j<4;j++){ float v = acc[i][j][r]; sv += v; sq += v*v; }
      #pragma unroll
      for(int msk=1; msk<16; msk<<=1){ sv += __shfl_xor(sv, msk); sq += __shfl_xor(sq, msk); }
      if(m_l == 0){ int mrow = i*16 + quad*4 + r; ssum[mrow][wave] = sv; ssq[mrow][wave] = sq; }
    }
  }
  __syncthreads();
  if(tid < 64){
    float s1 = ssum[tid][0]+ssum[tid][1]+ssum[tid][2]+ssum[tid][3];
    float s2 = ssq[tid][0]+ssq[tid][1]+ssq[tid][2]+ssq[tid][3];
    float mean = s1*(1.f/256.f);
    float var  = s2*(1.f/256.f) - mean*mean;
    ssum[tid][0] = mean;
    ssq[tid][0]  = rsqrtf(var + 1e-12f);
  }
  __syncthreads();
  #pragma unroll
  for(int i=0;i<4;i++){
    #pragma unroll
    for(int j=0;j<4;j++){
      int col = wn + j*16 + m_l;
      float gw = lnw[col], gb = lnb[col];
      #pragma unroll
      for(int r=0;r<4;r++){
        int mrow = i*16 + quad*4 + r;
        float mean = ssum[mrow][0], inv = ssq[mrow][0];
        out[(size_t)(rowg0+mrow)*256 + col] = (acc[i][j][r] - mean)*inv*gw + gb;
      }
    }
  }
}

// =================== launch ===================
extern "C" void kernel_launch(void* const* d_in, const int* in_sizes, int n_in,
                              void* d_out, int out_size, void* d_ws, size_t ws_size,
                              hipStream_t stream){
  const float* inp    = (const float*)d_in[0];
  const float* conv_w = (const float*)d_in[1];
  const float* conv_b = (const float*)d_in[2];
  const float* fm_w1  = (const float*)d_in[3];
  const float* fm_b1  = (const float*)d_in[4];
  const float* fm_w2  = (const float*)d_in[5];
  const float* fm_b2  = (const float*)d_in[6];
  const float* cm_w1  = (const float*)d_in[7];
  const float* cm_b1  = (const float*)d_in[8];
  const float* cm_w2  = (const float*)d_in[9];
  const float* cm_b2  = (const float*)d_in[10];
  const float* sm_w1  = (const float*)d_in[11];
  const float* sm_b1  = (const float*)d_in[12];
  const float* sm_w2  = (const float*)d_in[13];
  const float* sm_b2  = (const float*)d_in[14];
  const float* ln_w   = (const float*)d_in[15];
  const float* ln_b   = (const float*)d_in[16];
  const float* ff_w1  = (const float*)d_in[17];
  const float* ff_b1  = (const float*)d_in[18];
  const float* ff_w2  = (const float*)d_in[19];
  const float* ff_b2  = (const float*)d_in[20];
  const float* ffln_w = (const float*)d_in[21];
  const float* ffln_b = (const float*)d_in[22];
  float* out = (float*)d_out;

  const size_t NS = (size_t)B_ * NSEG_ * FREQ_ * H_;   // 15,335,424
  const size_t HN = (size_t)NSEG_ * 1152 * 1024;       // 30,670,848
  short* ws = (short*)d_ws;
  bf16*  b0   = (bf16*)ws;                  // region A
  bf16*  b1   = (bf16*)(ws + NS);
  bf16*  b2   = (bf16*)(ws + 2*NS);         // region B
  bf16*  b3   = (bf16*)(ws + 3*NS);
  short* H    = ws + 4*NS;                  // 61.3 MB
  short* B1t  = H + HN;                     // 27.3 MB
  short* B2r  = B1t + (size_t)26*1024*512;  // 13.6 MB
  short* B2i  = B2r + (size_t)26*256*1024;  // 6.8 MB
  short* fw1t = B2i + (size_t)26*256*512;   // 0.5 MB
  short* fw2t = fw1t + 262144;              // 0.5 MB
  short* B1sm = fw2t + 262144;              // 147 KB
  short* B2sm = B1sm + 73728;               // 147 KB
  short* B1fm = B2sm + 73728;               // 80 KB
  short* B2fm = B1fm + 39936;               // 104 KB
  float* cwT  = (float*)(B2fm + 53248);     // 240 KB
  float* hs   = (float*)b0;                 // 52.4 MB over region A
  bf16*  hsb  = (bf16*)H;                   // 26.2 MB over H
  short* hid  = (short*)b2;                 // 52.4 MB over region B

  // ---- weight repack (idempotent, every call) ----
  k_prep_b1<<<1664, 256, 0, stream>>>(cm_w1, B1t);
  k_prep_b2<<<832,  256, 0, stream>>>(cm_w2, B2r, B2i);
  k_transp <<<64,   256, 0, stream>>>(ff_w1, fw1t, 256, 1024);
  k_transp <<<64,   256, 0, stream>>>(ff_w2, fw2t, 1024, 256);
  k_prep_sm<<<9,    256, 0, stream>>>(sm_w1, sm_w2, B1sm, B2sm);
  k_prep_fm<<<26,   256, 0, stream>>>(fm_w1, fm_w2, B1fm, B2fm);
  k_prep_cw<<<26,   256, 0, stream>>>(conv_w, cwT);

  // ---- pipeline ----
  k_sfm2<<<B_*NSEG_, 256, 0, stream>>>(inp, cwT, conv_b, B1fm, B2fm, fm_b1, fm_b2, b2, b3);
  for(int half=0; half<2; half++){
    k_cm1<<<26*72, 256, 0, stream>>>(b2, b3, B1t, cm_b1, H, half);
    k_cm2<<<26*36, 256, 0, stream>>>(H, B2r, B2i, cm_b2, b0, b1, half);
  }
  k_smm<<<B_*2*FREQ_, 512, 0, stream>>>(b0, b1, B1sm, B2sm, sm_b1, sm_b2, b2, b3);
  k_ist8<<<B_*25, 256, 0, stream>>>(b2, b3, inp, ln_w, ln_b, hs, hsb);
  for(int c=0; c<2; c++){
    int row0 = c*25600;
    k_ff1m<<<1600, 256, 0, stream>>>((const short*)hsb, fw1t, ff_b1, hid, row0);
    k_ff2m<<<400,  256, 0, stream>>>(hid, fw2t, ff_b2, hs, ffln_w, ffln_b, out, row0);
  }
}